// Round 6
// baseline (2186.766 us; speedup 1.0000x reference)
//
#include <hip/hip_runtime.h>
#include <math.h>

#define NN 50000
#define NE 800000
#define IND 256
#define NH 64
#define DEPTH 4
#define PART_DIV 6250   // ceil(NN/8): node partition for XCD-local scatter

// ---------------- bf16 helpers ----------------

__device__ __forceinline__ unsigned short f2bf(float f) {
    unsigned int x = __float_as_uint(f);
    unsigned int r = (x + 0x7fffu + ((x >> 16) & 1u)) >> 16;
    return (unsigned short)r;
}
__device__ __forceinline__ unsigned int pack2bf(float lo, float hi) {
    return (unsigned int)f2bf(lo) | ((unsigned int)f2bf(hi) << 16);
}
__device__ __forceinline__ ushort4 f4_to_us4(float4 f) {
    ushort4 u;
    u.x = f2bf(f.x); u.y = f2bf(f.y); u.z = f2bf(f.z); u.w = f2bf(f.w);
    return u;
}
// unpack a uint4 (8 packed bf16) and accumulate into a[0..7]
__device__ __forceinline__ void acc8(float* a, uint4 r) {
    a[0] += __uint_as_float(r.x << 16); a[1] += __uint_as_float(r.x & 0xffff0000u);
    a[2] += __uint_as_float(r.y << 16); a[3] += __uint_as_float(r.y & 0xffff0000u);
    a[4] += __uint_as_float(r.z << 16); a[5] += __uint_as_float(r.z & 0xffff0000u);
    a[6] += __uint_as_float(r.w << 16); a[7] += __uint_as_float(r.w & 0xffff0000u);
}
__device__ __forceinline__ void unpack8(float* a, uint4 r) {
    a[0] = __uint_as_float(r.x << 16); a[1] = __uint_as_float(r.x & 0xffff0000u);
    a[2] = __uint_as_float(r.y << 16); a[3] = __uint_as_float(r.y & 0xffff0000u);
    a[4] = __uint_as_float(r.z << 16); a[5] = __uint_as_float(r.z & 0xffff0000u);
    a[6] = __uint_as_float(r.w << 16); a[7] = __uint_as_float(r.w & 0xffff0000u);
}
__device__ __forceinline__ void accd8(float* a, const float* xg, uint4 r) {
    float e;
    e = xg[0] - __uint_as_float(r.x << 16);         a[0] += e * e;
    e = xg[1] - __uint_as_float(r.x & 0xffff0000u); a[1] += e * e;
    e = xg[2] - __uint_as_float(r.y << 16);         a[2] += e * e;
    e = xg[3] - __uint_as_float(r.y & 0xffff0000u); a[3] += e * e;
    e = xg[4] - __uint_as_float(r.z << 16);         a[4] += e * e;
    e = xg[5] - __uint_as_float(r.z & 0xffff0000u); a[5] += e * e;
    e = xg[6] - __uint_as_float(r.w << 16);         a[6] += e * e;
    e = xg[7] - __uint_as_float(r.w & 0xffff0000u); a[7] += e * e;
}
// tanh for x>=0: (1-e^{-2x})/(1+e^{-2x})
__device__ __forceinline__ float tanh_pos(float x) {
    float t = __expf(-2.f * x);
    return (1.f - t) / (1.f + t);
}

// ---------------- CSR build ----------------

__global__ void count_deg(const int* __restrict__ src, const int* __restrict__ dst,
                          int* __restrict__ degin, int* __restrict__ degout) {
    int e = blockIdx.x * blockDim.x + threadIdx.x;
    if (e < NE) {
        atomicAdd(&degout[src[e]], 1);
        atomicAdd(&degin[dst[e]], 1);
    }
}

__global__ void scan2(const int* __restrict__ in0, int* __restrict__ out0,
                      const int* __restrict__ in1, int* __restrict__ out1, int n) {
    __shared__ int sums[1024];
    const int* in = blockIdx.x ? in1 : in0;
    int* out = blockIdx.x ? out1 : out0;
    int t = threadIdx.x;
    int chunk = (n + 1023) / 1024;
    int lo = t * chunk;
    int hi = lo + chunk; if (hi > n) hi = n;
    int s = 0;
    for (int i = lo; i < hi; ++i) s += in[i];
    sums[t] = s;
    __syncthreads();
    for (int off = 1; off < 1024; off <<= 1) {
        int v = (t >= off) ? sums[t - off] : 0;
        __syncthreads();
        sums[t] += v;
        __syncthreads();
    }
    int run = (t == 0) ? 0 : sums[t - 1];
    for (int i = lo; i < hi; ++i) { out[i] = run; run += in[i]; }
    if (t == 0) out[n] = sums[1023];
}

__global__ void init_node(const int* __restrict__ degin, const int* __restrict__ degout,
                          const int* __restrict__ off_dst, const int* __restrict__ off_src,
                          int* __restrict__ cur_dst, int* __restrict__ cur_src,
                          float* __restrict__ dis, float* __restrict__ cntf) {
    int i = blockIdx.x * blockDim.x + threadIdx.x;
    if (i < NN) {
        dis[i] = rsqrtf((float)(degin[i] + 1));   // +1 self loop; always >0
        int od = degout[i];
        cntf[i] = (float)(od > 0 ? od : 1);
        cur_dst[i] = off_dst[i];
        cur_src[i] = off_src[i];
    }
}

// XCD-partitioned scatter (kills write-allocate thrash; see r5 notes).
__global__ void fill_csr_part(const int* __restrict__ src, const int* __restrict__ dst,
                              int* __restrict__ cur_dst, int* __restrict__ cur_src,
                              int* __restrict__ srcs_by_dst, int* __restrict__ dsts_by_src,
                              int nGroups) {
    int p = blockIdx.x & 7;
    int g = blockIdx.x >> 3;
    for (int e = g * 256 + threadIdx.x; e < NE; e += nGroups * 256) {
        int s = src[e], d = dst[e];
        if (d / PART_DIV == p) {
            int pos = atomicAdd(&cur_dst[d], 1);
            srcs_by_dst[pos] = s;
        }
        if (s / PART_DIV == p) {
            int pos = atomicAdd(&cur_src[s], 1);
            dsts_by_src[pos] = d;
        }
    }
}

// ---------------- GEMM: [n,K] @ [K,64], 64 rows per block (enc/dec) ----------------
template<int K, bool RELU, bool WSC>
__global__ __launch_bounds__(256) void gemm64b(const float* __restrict__ X,
                                               const float* __restrict__ W,
                                               const float* __restrict__ bias,
                                               const float* __restrict__ rowscale,
                                               float* __restrict__ out,
                                               unsigned short* __restrict__ xsc, int n) {
    __shared__ float Ws[64 * 64];
    __shared__ float Xs[64][68];
    int tid = threadIdx.x;
    int row0 = blockIdx.x * 64;
    int r16 = tid >> 4;
    int cg = tid & 15;
    float4 acc[4];
#pragma unroll
    for (int t = 0; t < 4; ++t) acc[t] = make_float4(0.f, 0.f, 0.f, 0.f);

    for (int kc = 0; kc < K; kc += 64) {
        const float4* W4 = (const float4*)(W + (size_t)kc * 64);
        float4* Ws4 = (float4*)Ws;
#pragma unroll
        for (int t = 0; t < 4; ++t) Ws4[tid + t * 256] = W4[tid + t * 256];
#pragma unroll
        for (int t = 0; t < 4; ++t) {
            int r = r16 + t * 16;
            int grow = row0 + r;
            float4 xv = make_float4(0.f, 0.f, 0.f, 0.f);
            if (grow < n) xv = *(const float4*)(X + (size_t)grow * K + kc + cg * 4);
            Xs[r][cg * 4 + 0] = xv.x; Xs[r][cg * 4 + 1] = xv.y;
            Xs[r][cg * 4 + 2] = xv.z; Xs[r][cg * 4 + 3] = xv.w;
        }
        __syncthreads();
#pragma unroll
        for (int k = 0; k < 64; ++k) {
            float4 w4 = ((const float4*)Ws)[k * 16 + cg];
#pragma unroll
            for (int t = 0; t < 4; ++t) {
                float xv = Xs[r16 + t * 16][k];
                acc[t].x += xv * w4.x; acc[t].y += xv * w4.y;
                acc[t].z += xv * w4.z; acc[t].w += xv * w4.w;
            }
        }
        __syncthreads();
    }

    float4 b4 = ((const float4*)bias)[cg];
#pragma unroll
    for (int t = 0; t < 4; ++t) {
        int row = row0 + r16 + t * 16;
        if (row < n) {
            float4 o;
            o.x = acc[t].x + b4.x; o.y = acc[t].y + b4.y;
            o.z = acc[t].z + b4.z; o.w = acc[t].w + b4.w;
            if (RELU) {
                o.x = fmaxf(o.x, 0.f); o.y = fmaxf(o.y, 0.f);
                o.z = fmaxf(o.z, 0.f); o.w = fmaxf(o.w, 0.f);
            }
            ((float4*)(out + (size_t)row * 64))[cg] = o;
            if (WSC) {
                float s = rowscale[row];
                float4 o2 = make_float4(o.x * s, o.y * s, o.z * s, o.w * s);
                ((ushort4*)(xsc + (size_t)row * 64))[cg] = f4_to_us4(o2);
            }
        }
    }
}

// ---------------- zgather: node-per-octet, LDS-free ----------------
// Xbf (bf16) holds dis_i*X[i]. Z[i] = dis_i*(sum_{s in in(i)} Xbf[s] + Xbf[i]), fp32.
// 8 lanes = one node; lane l8 owns channels 8*l8..8*l8+7 (one dwordx4 per row).
// No cross-lane reduction, no LDS -> full occupancy, 32 loads in flight/wave.
__global__ __launch_bounds__(256) void zgather(
    const unsigned short* __restrict__ Xbf,
    const int* __restrict__ off, const int* __restrict__ nbr,
    const float* __restrict__ dis, float* __restrict__ Z)
{
    int t = blockIdx.x * 256 + threadIdx.x;
    int node = t >> 3, l8 = t & 7;
    if (node >= NN) return;
    const uint4* Xb = (const uint4*)Xbf;   // row = 8 uint4
    float a[8];
    unpack8(a, Xb[(size_t)node * 8 + l8]); // self (dis_i*X_i)
    int lo = off[node], hi = off[node + 1];
    int j = lo;
    for (; j + 3 < hi; j += 4) {
        int s0 = nbr[j], s1 = nbr[j + 1], s2 = nbr[j + 2], s3 = nbr[j + 3];
        uint4 r0 = Xb[(size_t)s0 * 8 + l8];
        uint4 r1 = Xb[(size_t)s1 * 8 + l8];
        uint4 r2 = Xb[(size_t)s2 * 8 + l8];
        uint4 r3 = Xb[(size_t)s3 * 8 + l8];
        acc8(a, r0); acc8(a, r1); acc8(a, r2); acc8(a, r3);
    }
    for (; j < hi; ++j) {
        acc8(a, Xb[(size_t)nbr[j] * 8 + l8]);
    }
    float di = dis[node];
    float* zp = Z + (size_t)node * 64 + l8 * 8;
    *(float4*)(zp)     = make_float4(di * a[0], di * a[1], di * a[2], di * a[3]);
    *(float4*)(zp + 4) = make_float4(di * a[4], di * a[5], di * a[6], di * a[7]);
}

// ---------------- dual GEMM: [n,64] @ 64x(64+64) ----------------
// B = relu(Z@Wb + bb) fp32 ; C = relu(Z@Wc + bc) bf16
__global__ __launch_bounds__(256) void dualgemm(
    const float* __restrict__ Z,
    const float* __restrict__ Wb, const float* __restrict__ bb,
    const float* __restrict__ Wc, const float* __restrict__ bc,
    float* __restrict__ B, unsigned short* __restrict__ Cbf, int n)
{
    __shared__ float Ws[2][64 * 64];
    __shared__ float Xs[64][68];
    int tid = threadIdx.x;
    int row0 = blockIdx.x * 64;
    int r16 = tid >> 4;
    int cg = tid & 15;
    {
        const float4* wb4 = (const float4*)Wb;
        const float4* wc4 = (const float4*)Wc;
        float4* s0 = (float4*)Ws[0];
        float4* s1 = (float4*)Ws[1];
#pragma unroll
        for (int t = 0; t < 4; ++t) {
            s0[tid + t * 256] = wb4[tid + t * 256];
            s1[tid + t * 256] = wc4[tid + t * 256];
        }
    }
#pragma unroll
    for (int t = 0; t < 4; ++t) {
        int r = r16 + t * 16;
        int grow = row0 + r;
        float4 xv = make_float4(0.f, 0.f, 0.f, 0.f);
        if (grow < n) xv = *(const float4*)(Z + (size_t)grow * 64 + cg * 4);
        Xs[r][cg * 4 + 0] = xv.x; Xs[r][cg * 4 + 1] = xv.y;
        Xs[r][cg * 4 + 2] = xv.z; Xs[r][cg * 4 + 3] = xv.w;
    }
    __syncthreads();

    float4 ab[4], ac[4];
#pragma unroll
    for (int t = 0; t < 4; ++t) {
        ab[t] = make_float4(0.f, 0.f, 0.f, 0.f);
        ac[t] = make_float4(0.f, 0.f, 0.f, 0.f);
    }
#pragma unroll
    for (int k = 0; k < 64; ++k) {
        float4 wb = ((const float4*)Ws[0])[k * 16 + cg];
        float4 wc = ((const float4*)Ws[1])[k * 16 + cg];
#pragma unroll
        for (int t = 0; t < 4; ++t) {
            float xv = Xs[r16 + t * 16][k];
            ab[t].x += xv * wb.x; ab[t].y += xv * wb.y;
            ab[t].z += xv * wb.z; ab[t].w += xv * wb.w;
            ac[t].x += xv * wc.x; ac[t].y += xv * wc.y;
            ac[t].z += xv * wc.z; ac[t].w += xv * wc.w;
        }
    }

    float4 bbv = ((const float4*)bb)[cg];
    float4 bcv = ((const float4*)bc)[cg];
#pragma unroll
    for (int t = 0; t < 4; ++t) {
        int row = row0 + r16 + t * 16;
        if (row < n) {
            float4 o;
            o.x = fmaxf(ab[t].x + bbv.x, 0.f); o.y = fmaxf(ab[t].y + bbv.y, 0.f);
            o.z = fmaxf(ab[t].z + bbv.z, 0.f); o.w = fmaxf(ab[t].w + bbv.w, 0.f);
            ((float4*)(B + (size_t)row * 64))[cg] = o;
            float4 c;
            c.x = fmaxf(ac[t].x + bcv.x, 0.f); c.y = fmaxf(ac[t].y + bcv.y, 0.f);
            c.z = fmaxf(ac[t].z + bcv.z, 0.f); c.w = fmaxf(ac[t].w + bcv.w, 0.f);
            ((ushort4*)(Cbf + (size_t)row * 64))[cg] = f4_to_us4(c);
        }
    }
}

// ---------------- gate + convex update: node-per-octet, LDS-free ----------------
// tau = tanh( sum_{d in out(i)} (xg_i - xg_d)^2 / cnt_i ) per channel
// X = (1-tau)*X + tau*Xn ; Xbf = bf16(dis*X) for next layer's gather
__global__ __launch_bounds__(256) void gate_update8(
    const unsigned short* __restrict__ Cbf, const float* __restrict__ Xn,
    float* __restrict__ X, unsigned short* __restrict__ Xbf,
    const int* __restrict__ off, const int* __restrict__ nbr,
    const float* __restrict__ cntf, const float* __restrict__ dis)
{
    int t = blockIdx.x * 256 + threadIdx.x;
    int node = t >> 3, l8 = t & 7;
    if (node >= NN) return;
    const uint4* Cb = (const uint4*)Cbf;
    float xg[8];
    unpack8(xg, Cb[(size_t)node * 8 + l8]);
    float a[8] = {0.f, 0.f, 0.f, 0.f, 0.f, 0.f, 0.f, 0.f};
    int lo = off[node], hi = off[node + 1];
    int j = lo;
    for (; j + 3 < hi; j += 4) {
        int d0 = nbr[j], d1 = nbr[j + 1], d2 = nbr[j + 2], d3 = nbr[j + 3];
        uint4 r0 = Cb[(size_t)d0 * 8 + l8];
        uint4 r1 = Cb[(size_t)d1 * 8 + l8];
        uint4 r2 = Cb[(size_t)d2 * 8 + l8];
        uint4 r3 = Cb[(size_t)d3 * 8 + l8];
        accd8(a, xg, r0); accd8(a, xg, r1); accd8(a, xg, r2); accd8(a, xg, r3);
    }
    for (; j < hi; ++j) {
        accd8(a, xg, Cb[(size_t)nbr[j] * 8 + l8]);
    }
    float inv = 1.f / cntf[node];
    float di = dis[node];
    const float* xop = X + (size_t)node * 64 + l8 * 8;
    const float* xnp = Xn + (size_t)node * 64 + l8 * 8;
    float o[8];
#pragma unroll
    for (int k = 0; k < 8; ++k) {
        float tau = tanh_pos(a[k] * inv);
        float xo = xop[k], xn = xnp[k];
        o[k] = xo + tau * (xn - xo);
    }
    float* xp = X + (size_t)node * 64 + l8 * 8;
    *(float4*)(xp)     = make_float4(o[0], o[1], o[2], o[3]);
    *(float4*)(xp + 4) = make_float4(o[4], o[5], o[6], o[7]);
    uint4 pk;
    pk.x = pack2bf(o[0] * di, o[1] * di);
    pk.y = pack2bf(o[2] * di, o[3] * di);
    pk.z = pack2bf(o[4] * di, o[5] * di);
    pk.w = pack2bf(o[6] * di, o[7] * di);
    ((uint4*)Xbf)[(size_t)node * 8 + l8] = pk;
}

// ---------------- launch ----------------

extern "C" void kernel_launch(void* const* d_in, const int* in_sizes, int n_in,
                              void* d_out, int out_size, void* d_ws, size_t ws_size,
                              hipStream_t stream) {
    const float* x      = (const float*)d_in[0];
    const int*   ei     = (const int*)d_in[1];
    const float* enc_w  = (const float*)d_in[2];
    const float* enc_b  = (const float*)d_in[3];
    const float* conv_w = (const float*)d_in[4];
    const float* conv_b = (const float*)d_in[5];
    const float* gg_w   = (const float*)d_in[6];
    const float* gg_b   = (const float*)d_in[7];
    const float* dec_w  = (const float*)d_in[8];
    const float* dec_b  = (const float*)d_in[9];
    float* out = (float*)d_out;

    const int* src = ei;
    const int* dst = ei + NE;

    char* p = (char*)d_ws;
    auto alloc = [&](size_t bytes) -> void* {
        void* r = (void*)p;
        p += (bytes + 255) & ~(size_t)255;
        return r;
    };
    float* X   = (float*)alloc((size_t)NN * 64 * 4);
    float* Zb  = (float*)alloc((size_t)NN * 64 * 4);           // Z (fp32)
    float* B   = (float*)alloc((size_t)NN * 64 * 4);           // X_ candidate (fp32)
    unsigned short* Xbf = (unsigned short*)alloc((size_t)NN * 64 * 2);  // dis*X, bf16
    unsigned short* Cbf = (unsigned short*)alloc((size_t)NN * 64 * 2);  // xg, bf16
    float* dis  = (float*)alloc((size_t)NN * 4);
    float* cntf = (float*)alloc((size_t)NN * 4);
    int* degin   = (int*)alloc((size_t)NN * 4);
    int* degout  = (int*)alloc((size_t)NN * 4);
    int* off_dst = (int*)alloc((size_t)(NN + 1) * 4);
    int* off_src = (int*)alloc((size_t)(NN + 1) * 4);
    int* cur_dst = (int*)alloc((size_t)NN * 4);
    int* cur_src = (int*)alloc((size_t)NN * 4);
    int* sbd     = (int*)alloc((size_t)NE * 4);   // srcs grouped by dst
    int* dbs     = (int*)alloc((size_t)NE * 4);   // dsts grouped by src

    hipMemsetAsync(degin, 0, (size_t)NN * 4, stream);
    hipMemsetAsync(degout, 0, (size_t)NN * 4, stream);

    const int EB = (NE + 255) / 256;
    const int NB = (NN + 255) / 256;
    count_deg<<<EB, 256, 0, stream>>>(src, dst, degin, degout);
    scan2<<<2, 1024, 0, stream>>>(degin, off_dst, degout, off_src, NN);
    init_node<<<NB, 256, 0, stream>>>(degin, degout, off_dst, off_src,
                                      cur_dst, cur_src, dis, cntf);
    const int NGROUPS = 104;
    fill_csr_part<<<8 * NGROUPS, 256, 0, stream>>>(src, dst, cur_dst, cur_src,
                                                   sbd, dbs, NGROUPS);

    const int GB = (NN + 63) / 64;                 // 64-row gemm blocks
    const int OB = ((NN * 8) + 255) / 256;         // octet-kernel blocks (8 thr/node)

    // encoder: X = relu(x@enc_w+b); Xbf = bf16(dis*X)
    gemm64b<IND, true, true><<<GB, 256, 0, stream>>>(x, enc_w, enc_b, dis, X, Xbf, NN);

    for (int l = 0; l < DEPTH; ++l) {
        zgather<<<OB, 256, 0, stream>>>(Xbf, off_dst, sbd, dis, Zb);
        dualgemm<<<GB, 256, 0, stream>>>(Zb, conv_w, conv_b, gg_w, gg_b, B, Cbf, NN);
        gate_update8<<<OB, 256, 0, stream>>>(Cbf, B, X, Xbf, off_src, dbs, cntf, dis);
    }

    // decoder
    gemm64b<NH, true, false><<<GB, 256, 0, stream>>>(X, dec_w, dec_b, nullptr, out, nullptr, NN);
}

// Round 7
// 764.721 us; speedup vs baseline: 2.8596x; 2.8596x over previous
//
#include <hip/hip_runtime.h>
#include <math.h>

#define NN 50000
#define NE 800000
#define IND 256
#define NH 64
#define DEPTH 4
#define PART_DIV 6250   // ceil(NN/8): node partition for XCD-local scatter

// ---------------- bf16 helpers ----------------

__device__ __forceinline__ unsigned short f2bf(float f) {
    unsigned int x = __float_as_uint(f);
    unsigned int r = (x + 0x7fffu + ((x >> 16) & 1u)) >> 16;
    return (unsigned short)r;
}
__device__ __forceinline__ unsigned int pack2bf(float lo, float hi) {
    return (unsigned int)f2bf(lo) | ((unsigned int)f2bf(hi) << 16);
}
__device__ __forceinline__ ushort4 f4_to_us4(float4 f) {
    ushort4 u;
    u.x = f2bf(f.x); u.y = f2bf(f.y); u.z = f2bf(f.z); u.w = f2bf(f.w);
    return u;
}
// unpack a uint4 (8 packed bf16) and accumulate into a[0..7]
__device__ __forceinline__ void acc8(float* a, uint4 r) {
    a[0] += __uint_as_float(r.x << 16); a[1] += __uint_as_float(r.x & 0xffff0000u);
    a[2] += __uint_as_float(r.y << 16); a[3] += __uint_as_float(r.y & 0xffff0000u);
    a[4] += __uint_as_float(r.z << 16); a[5] += __uint_as_float(r.z & 0xffff0000u);
    a[6] += __uint_as_float(r.w << 16); a[7] += __uint_as_float(r.w & 0xffff0000u);
}
__device__ __forceinline__ void unpack8(float* a, uint4 r) {
    a[0] = __uint_as_float(r.x << 16); a[1] = __uint_as_float(r.x & 0xffff0000u);
    a[2] = __uint_as_float(r.y << 16); a[3] = __uint_as_float(r.y & 0xffff0000u);
    a[4] = __uint_as_float(r.z << 16); a[5] = __uint_as_float(r.z & 0xffff0000u);
    a[6] = __uint_as_float(r.w << 16); a[7] = __uint_as_float(r.w & 0xffff0000u);
}
__device__ __forceinline__ void accd8(float* a, const float* xg, uint4 r) {
    float e;
    e = xg[0] - __uint_as_float(r.x << 16);         a[0] += e * e;
    e = xg[1] - __uint_as_float(r.x & 0xffff0000u); a[1] += e * e;
    e = xg[2] - __uint_as_float(r.y << 16);         a[2] += e * e;
    e = xg[3] - __uint_as_float(r.y & 0xffff0000u); a[3] += e * e;
    e = xg[4] - __uint_as_float(r.z << 16);         a[4] += e * e;
    e = xg[5] - __uint_as_float(r.z & 0xffff0000u); a[5] += e * e;
    e = xg[6] - __uint_as_float(r.w << 16);         a[6] += e * e;
    e = xg[7] - __uint_as_float(r.w & 0xffff0000u); a[7] += e * e;
}
// tanh for x>=0: (1-e^{-2x})/(1+e^{-2x})
__device__ __forceinline__ float tanh_pos(float x) {
    float t = __expf(-2.f * x);
    return (1.f - t) / (1.f + t);
}

// ---------------- CSR build ----------------

__global__ void count_deg(const int* __restrict__ src, const int* __restrict__ dst,
                          int* __restrict__ degin, int* __restrict__ degout) {
    int e = blockIdx.x * blockDim.x + threadIdx.x;
    if (e < NE) {
        atomicAdd(&degout[src[e]], 1);
        atomicAdd(&degin[dst[e]], 1);
    }
}

__global__ void scan2(const int* __restrict__ in0, int* __restrict__ out0,
                      const int* __restrict__ in1, int* __restrict__ out1, int n) {
    __shared__ int sums[1024];
    const int* in = blockIdx.x ? in1 : in0;
    int* out = blockIdx.x ? out1 : out0;
    int t = threadIdx.x;
    int chunk = (n + 1023) / 1024;
    int lo = t * chunk;
    int hi = lo + chunk; if (hi > n) hi = n;
    int s = 0;
    for (int i = lo; i < hi; ++i) s += in[i];
    sums[t] = s;
    __syncthreads();
    for (int off = 1; off < 1024; off <<= 1) {
        int v = (t >= off) ? sums[t - off] : 0;
        __syncthreads();
        sums[t] += v;
        __syncthreads();
    }
    int run = (t == 0) ? 0 : sums[t - 1];
    for (int i = lo; i < hi; ++i) { out[i] = run; run += in[i]; }
    if (t == 0) out[n] = sums[1023];
}

__global__ void init_node(const int* __restrict__ degin, const int* __restrict__ degout,
                          const int* __restrict__ off_dst, const int* __restrict__ off_src,
                          int* __restrict__ cur_dst, int* __restrict__ cur_src,
                          float* __restrict__ dis, float* __restrict__ cntf) {
    int i = blockIdx.x * blockDim.x + threadIdx.x;
    if (i < NN) {
        dis[i] = rsqrtf((float)(degin[i] + 1));   // +1 self loop; always >0
        int od = degout[i];
        cntf[i] = (float)(od > 0 ? od : 1);
        cur_dst[i] = off_dst[i];
        cur_src[i] = off_src[i];
    }
}

// XCD-partitioned scatter (kills write-allocate thrash; see r5 notes).
__global__ void fill_csr_part(const int* __restrict__ src, const int* __restrict__ dst,
                              int* __restrict__ cur_dst, int* __restrict__ cur_src,
                              int* __restrict__ srcs_by_dst, int* __restrict__ dsts_by_src,
                              int nGroups) {
    int p = blockIdx.x & 7;
    int g = blockIdx.x >> 3;
    for (int e = g * 256 + threadIdx.x; e < NE; e += nGroups * 256) {
        int s = src[e], d = dst[e];
        if (d / PART_DIV == p) {
            int pos = atomicAdd(&cur_dst[d], 1);
            srcs_by_dst[pos] = s;
        }
        if (s / PART_DIV == p) {
            int pos = atomicAdd(&cur_src[s], 1);
            dsts_by_src[pos] = d;
        }
    }
}

// ---------------- GEMM: [n,K] @ [K,64], 64 rows per block (enc/dec) ----------------
template<int K, bool RELU, bool WSC>
__global__ __launch_bounds__(256) void gemm64b(const float* __restrict__ X,
                                               const float* __restrict__ W,
                                               const float* __restrict__ bias,
                                               const float* __restrict__ rowscale,
                                               float* __restrict__ out,
                                               unsigned short* __restrict__ xsc, int n) {
    __shared__ float Ws[64 * 64];
    __shared__ float Xs[64][68];
    int tid = threadIdx.x;
    int row0 = blockIdx.x * 64;
    int r16 = tid >> 4;
    int cg = tid & 15;
    float4 acc[4];
#pragma unroll
    for (int t = 0; t < 4; ++t) acc[t] = make_float4(0.f, 0.f, 0.f, 0.f);

    for (int kc = 0; kc < K; kc += 64) {
        const float4* W4 = (const float4*)(W + (size_t)kc * 64);
        float4* Ws4 = (float4*)Ws;
#pragma unroll
        for (int t = 0; t < 4; ++t) Ws4[tid + t * 256] = W4[tid + t * 256];
#pragma unroll
        for (int t = 0; t < 4; ++t) {
            int r = r16 + t * 16;
            int grow = row0 + r;
            float4 xv = make_float4(0.f, 0.f, 0.f, 0.f);
            if (grow < n) xv = *(const float4*)(X + (size_t)grow * K + kc + cg * 4);
            Xs[r][cg * 4 + 0] = xv.x; Xs[r][cg * 4 + 1] = xv.y;
            Xs[r][cg * 4 + 2] = xv.z; Xs[r][cg * 4 + 3] = xv.w;
        }
        __syncthreads();
#pragma unroll
        for (int k = 0; k < 64; ++k) {
            float4 w4 = ((const float4*)Ws)[k * 16 + cg];
#pragma unroll
            for (int t = 0; t < 4; ++t) {
                float xv = Xs[r16 + t * 16][k];
                acc[t].x += xv * w4.x; acc[t].y += xv * w4.y;
                acc[t].z += xv * w4.z; acc[t].w += xv * w4.w;
            }
        }
        __syncthreads();
    }

    float4 b4 = ((const float4*)bias)[cg];
#pragma unroll
    for (int t = 0; t < 4; ++t) {
        int row = row0 + r16 + t * 16;
        if (row < n) {
            float4 o;
            o.x = acc[t].x + b4.x; o.y = acc[t].y + b4.y;
            o.z = acc[t].z + b4.z; o.w = acc[t].w + b4.w;
            if (RELU) {
                o.x = fmaxf(o.x, 0.f); o.y = fmaxf(o.y, 0.f);
                o.z = fmaxf(o.z, 0.f); o.w = fmaxf(o.w, 0.f);
            }
            ((float4*)(out + (size_t)row * 64))[cg] = o;
            if (WSC) {
                float s = rowscale[row];
                float4 o2 = make_float4(o.x * s, o.y * s, o.z * s, o.w * s);
                ((ushort4*)(xsc + (size_t)row * 64))[cg] = f4_to_us4(o2);
            }
        }
    }
}

// ---------------- gemm64z: [n,64] @ [64,64] + relu, fp32 or bf16 out ----------------
// Identical structure to gemm64b (known non-spilling: 16 acc regs, 33 KB LDS).
template<bool OUTBF>
__global__ __launch_bounds__(256) void gemm64z(const float* __restrict__ Z,
                                               const float* __restrict__ W,
                                               const float* __restrict__ bias,
                                               float* __restrict__ outf,
                                               unsigned short* __restrict__ outb, int n) {
    __shared__ float Ws[64 * 64];
    __shared__ float Xs[64][68];
    int tid = threadIdx.x;
    int row0 = blockIdx.x * 64;
    int r16 = tid >> 4;
    int cg = tid & 15;
    float4 acc[4];
#pragma unroll
    for (int t = 0; t < 4; ++t) acc[t] = make_float4(0.f, 0.f, 0.f, 0.f);

    {
        const float4* W4 = (const float4*)W;
        float4* Ws4 = (float4*)Ws;
#pragma unroll
        for (int t = 0; t < 4; ++t) Ws4[tid + t * 256] = W4[tid + t * 256];
#pragma unroll
        for (int t = 0; t < 4; ++t) {
            int r = r16 + t * 16;
            int grow = row0 + r;
            float4 xv = make_float4(0.f, 0.f, 0.f, 0.f);
            if (grow < n) xv = *(const float4*)(Z + (size_t)grow * 64 + cg * 4);
            Xs[r][cg * 4 + 0] = xv.x; Xs[r][cg * 4 + 1] = xv.y;
            Xs[r][cg * 4 + 2] = xv.z; Xs[r][cg * 4 + 3] = xv.w;
        }
        __syncthreads();
#pragma unroll
        for (int k = 0; k < 64; ++k) {
            float4 w4 = ((const float4*)Ws)[k * 16 + cg];
#pragma unroll
            for (int t = 0; t < 4; ++t) {
                float xv = Xs[r16 + t * 16][k];
                acc[t].x += xv * w4.x; acc[t].y += xv * w4.y;
                acc[t].z += xv * w4.z; acc[t].w += xv * w4.w;
            }
        }
    }

    float4 b4 = ((const float4*)bias)[cg];
#pragma unroll
    for (int t = 0; t < 4; ++t) {
        int row = row0 + r16 + t * 16;
        if (row < n) {
            float4 o;
            o.x = fmaxf(acc[t].x + b4.x, 0.f); o.y = fmaxf(acc[t].y + b4.y, 0.f);
            o.z = fmaxf(acc[t].z + b4.z, 0.f); o.w = fmaxf(acc[t].w + b4.w, 0.f);
            if (OUTBF) {
                ((ushort4*)(outb + (size_t)row * 64))[cg] = f4_to_us4(o);
            } else {
                ((float4*)(outf + (size_t)row * 64))[cg] = o;
            }
        }
    }
}

// ---------------- zgather: node-per-octet, LDS-free ----------------
// Xbf (bf16) holds dis_i*X[i]. Z[i] = dis_i*(sum_{s in in(i)} Xbf[s] + Xbf[i]), fp32.
// 8 lanes = one node; lane l8 owns channels 8*l8..8*l8+7 (one dwordx4 per row).
__global__ __launch_bounds__(256) void zgather(
    const unsigned short* __restrict__ Xbf,
    const int* __restrict__ off, const int* __restrict__ nbr,
    const float* __restrict__ dis, float* __restrict__ Z)
{
    int t = blockIdx.x * 256 + threadIdx.x;
    int node = t >> 3, l8 = t & 7;
    if (node >= NN) return;
    const uint4* Xb = (const uint4*)Xbf;   // row = 8 uint4
    float a[8];
    unpack8(a, Xb[(size_t)node * 8 + l8]); // self (dis_i*X_i)
    int lo = off[node], hi = off[node + 1];
    int j = lo;
    for (; j + 3 < hi; j += 4) {
        int s0 = nbr[j], s1 = nbr[j + 1], s2 = nbr[j + 2], s3 = nbr[j + 3];
        uint4 r0 = Xb[(size_t)s0 * 8 + l8];
        uint4 r1 = Xb[(size_t)s1 * 8 + l8];
        uint4 r2 = Xb[(size_t)s2 * 8 + l8];
        uint4 r3 = Xb[(size_t)s3 * 8 + l8];
        acc8(a, r0); acc8(a, r1); acc8(a, r2); acc8(a, r3);
    }
    for (; j < hi; ++j) {
        acc8(a, Xb[(size_t)nbr[j] * 8 + l8]);
    }
    float di = dis[node];
    float* zp = Z + (size_t)node * 64 + l8 * 8;
    *(float4*)(zp)     = make_float4(di * a[0], di * a[1], di * a[2], di * a[3]);
    *(float4*)(zp + 4) = make_float4(di * a[4], di * a[5], di * a[6], di * a[7]);
}

// ---------------- gate + convex update: node-per-octet, LDS-free ----------------
__global__ __launch_bounds__(256) void gate_update8(
    const unsigned short* __restrict__ Cbf, const float* __restrict__ Xn,
    float* __restrict__ X, unsigned short* __restrict__ Xbf,
    const int* __restrict__ off, const int* __restrict__ nbr,
    const float* __restrict__ cntf, const float* __restrict__ dis)
{
    int t = blockIdx.x * 256 + threadIdx.x;
    int node = t >> 3, l8 = t & 7;
    if (node >= NN) return;
    const uint4* Cb = (const uint4*)Cbf;
    float xg[8];
    unpack8(xg, Cb[(size_t)node * 8 + l8]);
    float a[8] = {0.f, 0.f, 0.f, 0.f, 0.f, 0.f, 0.f, 0.f};
    int lo = off[node], hi = off[node + 1];
    int j = lo;
    for (; j + 3 < hi; j += 4) {
        int d0 = nbr[j], d1 = nbr[j + 1], d2 = nbr[j + 2], d3 = nbr[j + 3];
        uint4 r0 = Cb[(size_t)d0 * 8 + l8];
        uint4 r1 = Cb[(size_t)d1 * 8 + l8];
        uint4 r2 = Cb[(size_t)d2 * 8 + l8];
        uint4 r3 = Cb[(size_t)d3 * 8 + l8];
        accd8(a, xg, r0); accd8(a, xg, r1); accd8(a, xg, r2); accd8(a, xg, r3);
    }
    for (; j < hi; ++j) {
        accd8(a, xg, Cb[(size_t)nbr[j] * 8 + l8]);
    }
    float inv = 1.f / cntf[node];
    float di = dis[node];
    const float* xop = X + (size_t)node * 64 + l8 * 8;
    const float* xnp = Xn + (size_t)node * 64 + l8 * 8;
    float o[8];
#pragma unroll
    for (int k = 0; k < 8; ++k) {
        float tau = tanh_pos(a[k] * inv);
        float xo = xop[k], xn = xnp[k];
        o[k] = xo + tau * (xn - xo);
    }
    float* xp = X + (size_t)node * 64 + l8 * 8;
    *(float4*)(xp)     = make_float4(o[0], o[1], o[2], o[3]);
    *(float4*)(xp + 4) = make_float4(o[4], o[5], o[6], o[7]);
    uint4 pk;
    pk.x = pack2bf(o[0] * di, o[1] * di);
    pk.y = pack2bf(o[2] * di, o[3] * di);
    pk.z = pack2bf(o[4] * di, o[5] * di);
    pk.w = pack2bf(o[6] * di, o[7] * di);
    ((uint4*)Xbf)[(size_t)node * 8 + l8] = pk;
}

// ---------------- launch ----------------

extern "C" void kernel_launch(void* const* d_in, const int* in_sizes, int n_in,
                              void* d_out, int out_size, void* d_ws, size_t ws_size,
                              hipStream_t stream) {
    const float* x      = (const float*)d_in[0];
    const int*   ei     = (const int*)d_in[1];
    const float* enc_w  = (const float*)d_in[2];
    const float* enc_b  = (const float*)d_in[3];
    const float* conv_w = (const float*)d_in[4];
    const float* conv_b = (const float*)d_in[5];
    const float* gg_w   = (const float*)d_in[6];
    const float* gg_b   = (const float*)d_in[7];
    const float* dec_w  = (const float*)d_in[8];
    const float* dec_b  = (const float*)d_in[9];
    float* out = (float*)d_out;

    const int* src = ei;
    const int* dst = ei + NE;

    char* p = (char*)d_ws;
    auto alloc = [&](size_t bytes) -> void* {
        void* r = (void*)p;
        p += (bytes + 255) & ~(size_t)255;
        return r;
    };
    float* X   = (float*)alloc((size_t)NN * 64 * 4);
    float* Zb  = (float*)alloc((size_t)NN * 64 * 4);           // Z (fp32)
    float* B   = (float*)alloc((size_t)NN * 64 * 4);           // X_ candidate (fp32)
    unsigned short* Xbf = (unsigned short*)alloc((size_t)NN * 64 * 2);  // dis*X, bf16
    unsigned short* Cbf = (unsigned short*)alloc((size_t)NN * 64 * 2);  // xg, bf16
    float* dis  = (float*)alloc((size_t)NN * 4);
    float* cntf = (float*)alloc((size_t)NN * 4);
    int* degin   = (int*)alloc((size_t)NN * 4);
    int* degout  = (int*)alloc((size_t)NN * 4);
    int* off_dst = (int*)alloc((size_t)(NN + 1) * 4);
    int* off_src = (int*)alloc((size_t)(NN + 1) * 4);
    int* cur_dst = (int*)alloc((size_t)NN * 4);
    int* cur_src = (int*)alloc((size_t)NN * 4);
    int* sbd     = (int*)alloc((size_t)NE * 4);   // srcs grouped by dst
    int* dbs     = (int*)alloc((size_t)NE * 4);   // dsts grouped by src

    hipMemsetAsync(degin, 0, (size_t)NN * 4, stream);
    hipMemsetAsync(degout, 0, (size_t)NN * 4, stream);

    const int EB = (NE + 255) / 256;
    const int NB = (NN + 255) / 256;
    count_deg<<<EB, 256, 0, stream>>>(src, dst, degin, degout);
    scan2<<<2, 1024, 0, stream>>>(degin, off_dst, degout, off_src, NN);
    init_node<<<NB, 256, 0, stream>>>(degin, degout, off_dst, off_src,
                                      cur_dst, cur_src, dis, cntf);
    const int NGROUPS = 104;
    fill_csr_part<<<8 * NGROUPS, 256, 0, stream>>>(src, dst, cur_dst, cur_src,
                                                   sbd, dbs, NGROUPS);

    const int GB = (NN + 63) / 64;                 // 64-row gemm blocks
    const int OB = ((NN * 8) + 255) / 256;         // octet-kernel blocks (8 thr/node)

    // encoder: X = relu(x@enc_w+b); Xbf = bf16(dis*X)
    gemm64b<IND, true, true><<<GB, 256, 0, stream>>>(x, enc_w, enc_b, dis, X, Xbf, NN);

    for (int l = 0; l < DEPTH; ++l) {
        zgather<<<OB, 256, 0, stream>>>(Xbf, off_dst, sbd, dis, Zb);
        gemm64z<false><<<GB, 256, 0, stream>>>(Zb, conv_w, conv_b, B, nullptr, NN);
        gemm64z<true><<<GB, 256, 0, stream>>>(Zb, gg_w, gg_b, nullptr, Cbf, NN);
        gate_update8<<<OB, 256, 0, stream>>>(Cbf, B, X, Xbf, off_src, dbs, cntf, dis);
    }

    // decoder
    gemm64b<NH, true, false><<<GB, 256, 0, stream>>>(X, dec_w, dec_b, nullptr, out, nullptr, NN);
}

// Round 8
// 697.147 us; speedup vs baseline: 3.1367x; 1.0969x over previous
//
#include <hip/hip_runtime.h>
#include <math.h>

#define NN 50000
#define NE 800000
#define IND 256
#define NH 64
#define DEPTH 4
#define PART_DIV 6250   // ceil(NN/8): node partition for XCD-local scatter
#define SB 49           // scan blocks per array (49*1024 >= NN)

// ---------------- bf16 helpers ----------------

__device__ __forceinline__ unsigned short f2bf(float f) {
    unsigned int x = __float_as_uint(f);
    unsigned int r = (x + 0x7fffu + ((x >> 16) & 1u)) >> 16;
    return (unsigned short)r;
}
__device__ __forceinline__ unsigned int pack2bf(float lo, float hi) {
    return (unsigned int)f2bf(lo) | ((unsigned int)f2bf(hi) << 16);
}
__device__ __forceinline__ ushort4 f4_to_us4(float4 f) {
    ushort4 u;
    u.x = f2bf(f.x); u.y = f2bf(f.y); u.z = f2bf(f.z); u.w = f2bf(f.w);
    return u;
}
__device__ __forceinline__ void acc8(float* a, uint4 r) {
    a[0] += __uint_as_float(r.x << 16); a[1] += __uint_as_float(r.x & 0xffff0000u);
    a[2] += __uint_as_float(r.y << 16); a[3] += __uint_as_float(r.y & 0xffff0000u);
    a[4] += __uint_as_float(r.z << 16); a[5] += __uint_as_float(r.z & 0xffff0000u);
    a[6] += __uint_as_float(r.w << 16); a[7] += __uint_as_float(r.w & 0xffff0000u);
}
__device__ __forceinline__ void unpack8(float* a, uint4 r) {
    a[0] = __uint_as_float(r.x << 16); a[1] = __uint_as_float(r.x & 0xffff0000u);
    a[2] = __uint_as_float(r.y << 16); a[3] = __uint_as_float(r.y & 0xffff0000u);
    a[4] = __uint_as_float(r.z << 16); a[5] = __uint_as_float(r.z & 0xffff0000u);
    a[6] = __uint_as_float(r.w << 16); a[7] = __uint_as_float(r.w & 0xffff0000u);
}
__device__ __forceinline__ void accd8(float* a, const float* xg, uint4 r) {
    float e;
    e = xg[0] - __uint_as_float(r.x << 16);         a[0] += e * e;
    e = xg[1] - __uint_as_float(r.x & 0xffff0000u); a[1] += e * e;
    e = xg[2] - __uint_as_float(r.y << 16);         a[2] += e * e;
    e = xg[3] - __uint_as_float(r.y & 0xffff0000u); a[3] += e * e;
    e = xg[4] - __uint_as_float(r.z << 16);         a[4] += e * e;
    e = xg[5] - __uint_as_float(r.z & 0xffff0000u); a[5] += e * e;
    e = xg[6] - __uint_as_float(r.w << 16);         a[6] += e * e;
    e = xg[7] - __uint_as_float(r.w & 0xffff0000u); a[7] += e * e;
}
__device__ __forceinline__ float tanh_pos(float x) {
    float t = __expf(-2.f * x);
    return (1.f - t) / (1.f + t);
}

// ---------------- CSR build ----------------

// XCD-partitioned degree count (atomics stay L2-local; edge list re-read 8x).
__global__ void count_deg_part(const int* __restrict__ src, const int* __restrict__ dst,
                               int* __restrict__ degin, int* __restrict__ degout,
                               int nGroups) {
    int p = blockIdx.x & 7;
    int g = blockIdx.x >> 3;
    for (int e = g * 256 + threadIdx.x; e < NE; e += nGroups * 256) {
        int s = src[e], d = dst[e];
        if (d / PART_DIV == p) atomicAdd(&degin[d], 1);
        if (s / PART_DIV == p) atomicAdd(&degout[s], 1);
    }
}

// -------- parallel exclusive scan, 3 phases, two arrays at once --------
// phase 1: block b of array a scans its 1024 elements (2/thread), writes
// per-element exclusive-in-block to tmp and block total to bsum.
__global__ __launch_bounds__(512) void scan_p1(const int* __restrict__ in0,
                                               const int* __restrict__ in1,
                                               int* __restrict__ tmp,
                                               int* __restrict__ bsum) {
    int a = blockIdx.x / SB;
    int b = blockIdx.x % SB;
    const int* in = a ? in1 : in0;
    int t = threadIdx.x;
    int base = b * 1024 + t * 2;
    int v0 = (base < NN) ? in[base] : 0;
    int v1 = (base + 1 < NN) ? in[base + 1] : 0;
    int v = v0 + v1;
    int x = v;
#pragma unroll
    for (int off = 1; off < 64; off <<= 1) {
        int u = __shfl_up(x, off);
        if ((t & 63) >= off) x += u;
    }
    __shared__ int ws[8];
    int wid = t >> 6, lane = t & 63;
    if (lane == 63) ws[wid] = x;
    __syncthreads();
    if (t == 0) {
        int run = 0;
#pragma unroll
        for (int w = 0; w < 8; ++w) { int s = ws[w]; ws[w] = run; run += s; }
    }
    __syncthreads();
    x += ws[wid];              // inclusive over block
    int excl = x - v;
    if (base < NN) tmp[a * NN + base] = excl;
    if (base + 1 < NN) tmp[a * NN + base + 1] = excl + v0;
    if (t == 511) bsum[a * SB + b] = x;   // block total
}

// phase 2: one wave per array scans the SB block sums; writes totals to out[NN].
__global__ __launch_bounds__(128) void scan_p2(int* __restrict__ bsum,
                                               int* __restrict__ out0,
                                               int* __restrict__ out1) {
    int t = threadIdx.x;
    int a = t >> 6, lane = t & 63;
    int v = (lane < SB) ? bsum[a * SB + lane] : 0;
    int x = v;
#pragma unroll
    for (int off = 1; off < 64; off <<= 1) {
        int u = __shfl_up(x, off);
        if (lane >= off) x += u;
    }
    if (lane < SB) bsum[a * SB + lane] = x - v;   // exclusive
    if (lane == SB - 1) {
        if (a == 0) out0[NN] = x; else out1[NN] = x;   // grand total
    }
}

// phase 3: out[i] = tmp[i] + scanned block sum.
__global__ __launch_bounds__(512) void scan_p3(const int* __restrict__ tmp,
                                               const int* __restrict__ bsum,
                                               int* __restrict__ out0,
                                               int* __restrict__ out1) {
    int a = blockIdx.x / SB;
    int b = blockIdx.x % SB;
    int* out = a ? out1 : out0;
    int add = bsum[a * SB + b];
    int t = threadIdx.x;
    int base = b * 1024 + t * 2;
    if (base < NN) out[base] = tmp[a * NN + base] + add;
    if (base + 1 < NN) out[base + 1] = tmp[a * NN + base + 1] + add;
}

__global__ void init_node(const int* __restrict__ degin, const int* __restrict__ degout,
                          const int* __restrict__ off_dst, const int* __restrict__ off_src,
                          int* __restrict__ cur_dst, int* __restrict__ cur_src,
                          float* __restrict__ dis, float* __restrict__ cntf) {
    int i = blockIdx.x * blockDim.x + threadIdx.x;
    if (i < NN) {
        dis[i] = rsqrtf((float)(degin[i] + 1));   // +1 self loop; always >0
        int od = degout[i];
        cntf[i] = (float)(od > 0 ? od : 1);
        cur_dst[i] = off_dst[i];
        cur_src[i] = off_src[i];
    }
}

// XCD-partitioned scatter (kills write-allocate thrash; see r5 notes).
__global__ void fill_csr_part(const int* __restrict__ src, const int* __restrict__ dst,
                              int* __restrict__ cur_dst, int* __restrict__ cur_src,
                              int* __restrict__ srcs_by_dst, int* __restrict__ dsts_by_src,
                              int nGroups) {
    int p = blockIdx.x & 7;
    int g = blockIdx.x >> 3;
    for (int e = g * 256 + threadIdx.x; e < NE; e += nGroups * 256) {
        int s = src[e], d = dst[e];
        if (d / PART_DIV == p) {
            int pos = atomicAdd(&cur_dst[d], 1);
            srcs_by_dst[pos] = s;
        }
        if (s / PART_DIV == p) {
            int pos = atomicAdd(&cur_src[s], 1);
            dsts_by_src[pos] = d;
        }
    }
}

// ---------------- GEMM: [n,K] @ [K,64], 64 rows per block (enc/dec) ----------------
template<int K, bool RELU, bool WSC>
__global__ __launch_bounds__(256) void gemm64b(const float* __restrict__ X,
                                               const float* __restrict__ W,
                                               const float* __restrict__ bias,
                                               const float* __restrict__ rowscale,
                                               float* __restrict__ out,
                                               unsigned short* __restrict__ xsc, int n) {
    __shared__ float Ws[64 * 64];
    __shared__ float Xs[64][68];
    int tid = threadIdx.x;
    int row0 = blockIdx.x * 64;
    int r16 = tid >> 4;
    int cg = tid & 15;
    float4 acc[4];
#pragma unroll
    for (int t = 0; t < 4; ++t) acc[t] = make_float4(0.f, 0.f, 0.f, 0.f);

    for (int kc = 0; kc < K; kc += 64) {
        const float4* W4 = (const float4*)(W + (size_t)kc * 64);
        float4* Ws4 = (float4*)Ws;
#pragma unroll
        for (int t = 0; t < 4; ++t) Ws4[tid + t * 256] = W4[tid + t * 256];
#pragma unroll
        for (int t = 0; t < 4; ++t) {
            int r = r16 + t * 16;
            int grow = row0 + r;
            float4 xv = make_float4(0.f, 0.f, 0.f, 0.f);
            if (grow < n) xv = *(const float4*)(X + (size_t)grow * K + kc + cg * 4);
            Xs[r][cg * 4 + 0] = xv.x; Xs[r][cg * 4 + 1] = xv.y;
            Xs[r][cg * 4 + 2] = xv.z; Xs[r][cg * 4 + 3] = xv.w;
        }
        __syncthreads();
#pragma unroll
        for (int k = 0; k < 64; ++k) {
            float4 w4 = ((const float4*)Ws)[k * 16 + cg];
#pragma unroll
            for (int t = 0; t < 4; ++t) {
                float xv = Xs[r16 + t * 16][k];
                acc[t].x += xv * w4.x; acc[t].y += xv * w4.y;
                acc[t].z += xv * w4.z; acc[t].w += xv * w4.w;
            }
        }
        __syncthreads();
    }

    float4 b4 = ((const float4*)bias)[cg];
#pragma unroll
    for (int t = 0; t < 4; ++t) {
        int row = row0 + r16 + t * 16;
        if (row < n) {
            float4 o;
            o.x = acc[t].x + b4.x; o.y = acc[t].y + b4.y;
            o.z = acc[t].z + b4.z; o.w = acc[t].w + b4.w;
            if (RELU) {
                o.x = fmaxf(o.x, 0.f); o.y = fmaxf(o.y, 0.f);
                o.z = fmaxf(o.z, 0.f); o.w = fmaxf(o.w, 0.f);
            }
            ((float4*)(out + (size_t)row * 64))[cg] = o;
            if (WSC) {
                float s = rowscale[row];
                float4 o2 = make_float4(o.x * s, o.y * s, o.z * s, o.w * s);
                ((ushort4*)(xsc + (size_t)row * 64))[cg] = f4_to_us4(o2);
            }
        }
    }
}

// ---------------- gemm64z: [n,64] @ [64,64] + relu, fp32 or bf16 out ----------------
template<bool OUTBF>
__global__ __launch_bounds__(256) void gemm64z(const float* __restrict__ Z,
                                               const float* __restrict__ W,
                                               const float* __restrict__ bias,
                                               float* __restrict__ outf,
                                               unsigned short* __restrict__ outb, int n) {
    __shared__ float Ws[64 * 64];
    __shared__ float Xs[64][68];
    int tid = threadIdx.x;
    int row0 = blockIdx.x * 64;
    int r16 = tid >> 4;
    int cg = tid & 15;
    float4 acc[4];
#pragma unroll
    for (int t = 0; t < 4; ++t) acc[t] = make_float4(0.f, 0.f, 0.f, 0.f);

    {
        const float4* W4 = (const float4*)W;
        float4* Ws4 = (float4*)Ws;
#pragma unroll
        for (int t = 0; t < 4; ++t) Ws4[tid + t * 256] = W4[tid + t * 256];
#pragma unroll
        for (int t = 0; t < 4; ++t) {
            int r = r16 + t * 16;
            int grow = row0 + t * 16 + r16;
            (void)grow;
            int gr = row0 + r;
            float4 xv = make_float4(0.f, 0.f, 0.f, 0.f);
            if (gr < n) xv = *(const float4*)(Z + (size_t)gr * 64 + cg * 4);
            Xs[r][cg * 4 + 0] = xv.x; Xs[r][cg * 4 + 1] = xv.y;
            Xs[r][cg * 4 + 2] = xv.z; Xs[r][cg * 4 + 3] = xv.w;
        }
        __syncthreads();
#pragma unroll
        for (int k = 0; k < 64; ++k) {
            float4 w4 = ((const float4*)Ws)[k * 16 + cg];
#pragma unroll
            for (int t = 0; t < 4; ++t) {
                float xv = Xs[r16 + t * 16][k];
                acc[t].x += xv * w4.x; acc[t].y += xv * w4.y;
                acc[t].z += xv * w4.z; acc[t].w += xv * w4.w;
            }
        }
    }

    float4 b4 = ((const float4*)bias)[cg];
#pragma unroll
    for (int t = 0; t < 4; ++t) {
        int row = row0 + r16 + t * 16;
        if (row < n) {
            float4 o;
            o.x = fmaxf(acc[t].x + b4.x, 0.f); o.y = fmaxf(acc[t].y + b4.y, 0.f);
            o.z = fmaxf(acc[t].z + b4.z, 0.f); o.w = fmaxf(acc[t].w + b4.w, 0.f);
            if (OUTBF) {
                ((ushort4*)(outb + (size_t)row * 64))[cg] = f4_to_us4(o);
            } else {
                ((float4*)(outf + (size_t)row * 64))[cg] = o;
            }
        }
    }
}

// ---------------- zgather: node-per-octet, LDS-free ----------------
__global__ __launch_bounds__(256) void zgather(
    const unsigned short* __restrict__ Xbf,
    const int* __restrict__ off, const int* __restrict__ nbr,
    const float* __restrict__ dis, float* __restrict__ Z)
{
    int t = blockIdx.x * 256 + threadIdx.x;
    int node = t >> 3, l8 = t & 7;
    if (node >= NN) return;
    const uint4* Xb = (const uint4*)Xbf;   // row = 8 uint4
    float a[8];
    unpack8(a, Xb[(size_t)node * 8 + l8]); // self (dis_i*X_i)
    int lo = off[node], hi = off[node + 1];
    int j = lo;
    for (; j + 3 < hi; j += 4) {
        int s0 = nbr[j], s1 = nbr[j + 1], s2 = nbr[j + 2], s3 = nbr[j + 3];
        uint4 r0 = Xb[(size_t)s0 * 8 + l8];
        uint4 r1 = Xb[(size_t)s1 * 8 + l8];
        uint4 r2 = Xb[(size_t)s2 * 8 + l8];
        uint4 r3 = Xb[(size_t)s3 * 8 + l8];
        acc8(a, r0); acc8(a, r1); acc8(a, r2); acc8(a, r3);
    }
    for (; j < hi; ++j) {
        acc8(a, Xb[(size_t)nbr[j] * 8 + l8]);
    }
    float di = dis[node];
    float* zp = Z + (size_t)node * 64 + l8 * 8;
    *(float4*)(zp)     = make_float4(di * a[0], di * a[1], di * a[2], di * a[3]);
    *(float4*)(zp + 4) = make_float4(di * a[4], di * a[5], di * a[6], di * a[7]);
}

// ---------------- gate + convex update: node-per-octet, LDS-free ----------------
__global__ __launch_bounds__(256) void gate_update8(
    const unsigned short* __restrict__ Cbf, const float* __restrict__ Xn,
    float* __restrict__ X, unsigned short* __restrict__ Xbf,
    const int* __restrict__ off, const int* __restrict__ nbr,
    const float* __restrict__ cntf, const float* __restrict__ dis)
{
    int t = blockIdx.x * 256 + threadIdx.x;
    int node = t >> 3, l8 = t & 7;
    if (node >= NN) return;
    const uint4* Cb = (const uint4*)Cbf;
    float xg[8];
    unpack8(xg, Cb[(size_t)node * 8 + l8]);
    float a[8] = {0.f, 0.f, 0.f, 0.f, 0.f, 0.f, 0.f, 0.f};
    int lo = off[node], hi = off[node + 1];
    int j = lo;
    for (; j + 3 < hi; j += 4) {
        int d0 = nbr[j], d1 = nbr[j + 1], d2 = nbr[j + 2], d3 = nbr[j + 3];
        uint4 r0 = Cb[(size_t)d0 * 8 + l8];
        uint4 r1 = Cb[(size_t)d1 * 8 + l8];
        uint4 r2 = Cb[(size_t)d2 * 8 + l8];
        uint4 r3 = Cb[(size_t)d3 * 8 + l8];
        accd8(a, xg, r0); accd8(a, xg, r1); accd8(a, xg, r2); accd8(a, xg, r3);
    }
    for (; j < hi; ++j) {
        accd8(a, xg, Cb[(size_t)nbr[j] * 8 + l8]);
    }
    float inv = 1.f / cntf[node];
    float di = dis[node];
    const float* xop = X + (size_t)node * 64 + l8 * 8;
    const float* xnp = Xn + (size_t)node * 64 + l8 * 8;
    float o[8];
#pragma unroll
    for (int k = 0; k < 8; ++k) {
        float tau = tanh_pos(a[k] * inv);
        float xo = xop[k], xn = xnp[k];
        o[k] = xo + tau * (xn - xo);
    }
    float* xp = X + (size_t)node * 64 + l8 * 8;
    *(float4*)(xp)     = make_float4(o[0], o[1], o[2], o[3]);
    *(float4*)(xp + 4) = make_float4(o[4], o[5], o[6], o[7]);
    uint4 pk;
    pk.x = pack2bf(o[0] * di, o[1] * di);
    pk.y = pack2bf(o[2] * di, o[3] * di);
    pk.z = pack2bf(o[4] * di, o[5] * di);
    pk.w = pack2bf(o[6] * di, o[7] * di);
    ((uint4*)Xbf)[(size_t)node * 8 + l8] = pk;
}

// ---------------- launch ----------------

extern "C" void kernel_launch(void* const* d_in, const int* in_sizes, int n_in,
                              void* d_out, int out_size, void* d_ws, size_t ws_size,
                              hipStream_t stream) {
    const float* x      = (const float*)d_in[0];
    const int*   ei     = (const int*)d_in[1];
    const float* enc_w  = (const float*)d_in[2];
    const float* enc_b  = (const float*)d_in[3];
    const float* conv_w = (const float*)d_in[4];
    const float* conv_b = (const float*)d_in[5];
    const float* gg_w   = (const float*)d_in[6];
    const float* gg_b   = (const float*)d_in[7];
    const float* dec_w  = (const float*)d_in[8];
    const float* dec_b  = (const float*)d_in[9];
    float* out = (float*)d_out;

    const int* src = ei;
    const int* dst = ei + NE;

    char* p = (char*)d_ws;
    auto alloc = [&](size_t bytes) -> void* {
        void* r = (void*)p;
        p += (bytes + 255) & ~(size_t)255;
        return r;
    };
    float* X   = (float*)alloc((size_t)NN * 64 * 4);
    float* Zb  = (float*)alloc((size_t)NN * 64 * 4);           // Z (fp32)
    float* B   = (float*)alloc((size_t)NN * 64 * 4);           // X_ candidate (fp32)
    unsigned short* Xbf = (unsigned short*)alloc((size_t)NN * 64 * 2);  // dis*X, bf16
    unsigned short* Cbf = (unsigned short*)alloc((size_t)NN * 64 * 2);  // xg, bf16
    float* dis  = (float*)alloc((size_t)NN * 4);
    float* cntf = (float*)alloc((size_t)NN * 4);
    int* degin   = (int*)alloc((size_t)NN * 4);
    int* degout  = (int*)alloc((size_t)NN * 4);
    int* off_dst = (int*)alloc((size_t)(NN + 1) * 4);
    int* off_src = (int*)alloc((size_t)(NN + 1) * 4);
    int* cur_dst = (int*)alloc((size_t)NN * 4);
    int* cur_src = (int*)alloc((size_t)NN * 4);
    int* sbd     = (int*)alloc((size_t)NE * 4);   // srcs grouped by dst
    int* dbs     = (int*)alloc((size_t)NE * 4);   // dsts grouped by src
    int* stmp    = (int*)alloc((size_t)2 * NN * 4);  // scan temp
    int* bsum    = (int*)alloc((size_t)2 * SB * 4);  // scan block sums

    hipMemsetAsync(degin, 0, (size_t)NN * 4, stream);
    hipMemsetAsync(degout, 0, (size_t)NN * 4, stream);

    const int NB = (NN + 255) / 256;
    const int NGROUPS = 104;
    count_deg_part<<<8 * NGROUPS, 256, 0, stream>>>(src, dst, degin, degout, NGROUPS);
    scan_p1<<<2 * SB, 512, 0, stream>>>(degin, degout, stmp, bsum);
    scan_p2<<<1, 128, 0, stream>>>(bsum, off_dst, off_src);
    scan_p3<<<2 * SB, 512, 0, stream>>>(stmp, bsum, off_dst, off_src);
    init_node<<<NB, 256, 0, stream>>>(degin, degout, off_dst, off_src,
                                      cur_dst, cur_src, dis, cntf);
    fill_csr_part<<<8 * NGROUPS, 256, 0, stream>>>(src, dst, cur_dst, cur_src,
                                                   sbd, dbs, NGROUPS);

    const int GB = (NN + 63) / 64;                 // 64-row gemm blocks
    const int OB = ((NN * 8) + 255) / 256;         // octet-kernel blocks (8 thr/node)

    // encoder: X = relu(x@enc_w+b); Xbf = bf16(dis*X)
    gemm64b<IND, true, true><<<GB, 256, 0, stream>>>(x, enc_w, enc_b, dis, X, Xbf, NN);

    for (int l = 0; l < DEPTH; ++l) {
        zgather<<<OB, 256, 0, stream>>>(Xbf, off_dst, sbd, dis, Zb);
        gemm64z<false><<<GB, 256, 0, stream>>>(Zb, conv_w, conv_b, B, nullptr, NN);
        gemm64z<true><<<GB, 256, 0, stream>>>(Zb, gg_w, gg_b, nullptr, Cbf, NN);
        gate_update8<<<OB, 256, 0, stream>>>(Cbf, B, X, Xbf, off_src, dbs, cntf, dis);
    }

    // decoder
    gemm64b<NH, true, false><<<GB, 256, 0, stream>>>(X, dec_w, dec_b, nullptr, out, nullptr, NN);
}

// Round 9
// 680.117 us; speedup vs baseline: 3.2153x; 1.0250x over previous
//
#include <hip/hip_runtime.h>
#include <math.h>

#define NN 50000
#define NE 800000
#define IND 256
#define NH 64
#define DEPTH 4
#define PART_DIV 6250   // ceil(NN/8): node partition for XCD-local scatter
#define SB 49           // scan blocks per array (49*1024 >= NN)

// ---------------- bf16 helpers ----------------

__device__ __forceinline__ unsigned short f2bf(float f) {
    unsigned int x = __float_as_uint(f);
    unsigned int r = (x + 0x7fffu + ((x >> 16) & 1u)) >> 16;
    return (unsigned short)r;
}
__device__ __forceinline__ unsigned int pack2bf(float lo, float hi) {
    return (unsigned int)f2bf(lo) | ((unsigned int)f2bf(hi) << 16);
}
__device__ __forceinline__ ushort4 f4_to_us4(float4 f) {
    ushort4 u;
    u.x = f2bf(f.x); u.y = f2bf(f.y); u.z = f2bf(f.z); u.w = f2bf(f.w);
    return u;
}
__device__ __forceinline__ void acc8(float* a, uint4 r) {
    a[0] += __uint_as_float(r.x << 16); a[1] += __uint_as_float(r.x & 0xffff0000u);
    a[2] += __uint_as_float(r.y << 16); a[3] += __uint_as_float(r.y & 0xffff0000u);
    a[4] += __uint_as_float(r.z << 16); a[5] += __uint_as_float(r.z & 0xffff0000u);
    a[6] += __uint_as_float(r.w << 16); a[7] += __uint_as_float(r.w & 0xffff0000u);
}
__device__ __forceinline__ void unpack8(float* a, uint4 r) {
    a[0] = __uint_as_float(r.x << 16); a[1] = __uint_as_float(r.x & 0xffff0000u);
    a[2] = __uint_as_float(r.y << 16); a[3] = __uint_as_float(r.y & 0xffff0000u);
    a[4] = __uint_as_float(r.z << 16); a[5] = __uint_as_float(r.z & 0xffff0000u);
    a[6] = __uint_as_float(r.w << 16); a[7] = __uint_as_float(r.w & 0xffff0000u);
}
__device__ __forceinline__ void accd8(float* a, const float* xg, uint4 r) {
    float e;
    e = xg[0] - __uint_as_float(r.x << 16);         a[0] += e * e;
    e = xg[1] - __uint_as_float(r.x & 0xffff0000u); a[1] += e * e;
    e = xg[2] - __uint_as_float(r.y << 16);         a[2] += e * e;
    e = xg[3] - __uint_as_float(r.y & 0xffff0000u); a[3] += e * e;
    e = xg[4] - __uint_as_float(r.z << 16);         a[4] += e * e;
    e = xg[5] - __uint_as_float(r.z & 0xffff0000u); a[5] += e * e;
    e = xg[6] - __uint_as_float(r.w << 16);         a[6] += e * e;
    e = xg[7] - __uint_as_float(r.w & 0xffff0000u); a[7] += e * e;
}
__device__ __forceinline__ float tanh_pos(float x) {
    float t = __expf(-2.f * x);
    return (1.f - t) / (1.f + t);
}

// ---------------- CSR build ----------------

// Unpartitioned count; the atomic return value IS the edge's rank within its
// node. rank writes are dense & coalesced (this is why count must NOT be
// partitioned — partitioned rank writes would ping-pong lines across XCDs).
__global__ void count_deg_rank(const int* __restrict__ src, const int* __restrict__ dst,
                               int* __restrict__ degin, int* __restrict__ degout,
                               int* __restrict__ rank_in, int* __restrict__ rank_out) {
    int e = blockIdx.x * blockDim.x + threadIdx.x;
    if (e < NE) {
        int s = src[e], d = dst[e];
        rank_in[e]  = atomicAdd(&degin[d], 1);
        rank_out[e] = atomicAdd(&degout[s], 1);
    }
}

// -------- parallel exclusive scan, 3 phases, two arrays at once --------
__global__ __launch_bounds__(512) void scan_p1(const int* __restrict__ in0,
                                               const int* __restrict__ in1,
                                               int* __restrict__ tmp,
                                               int* __restrict__ bsum) {
    int a = blockIdx.x / SB;
    int b = blockIdx.x % SB;
    const int* in = a ? in1 : in0;
    int t = threadIdx.x;
    int base = b * 1024 + t * 2;
    int v0 = (base < NN) ? in[base] : 0;
    int v1 = (base + 1 < NN) ? in[base + 1] : 0;
    int v = v0 + v1;
    int x = v;
#pragma unroll
    for (int off = 1; off < 64; off <<= 1) {
        int u = __shfl_up(x, off);
        if ((t & 63) >= off) x += u;
    }
    __shared__ int ws[8];
    int wid = t >> 6, lane = t & 63;
    if (lane == 63) ws[wid] = x;
    __syncthreads();
    if (t == 0) {
        int run = 0;
#pragma unroll
        for (int w = 0; w < 8; ++w) { int s = ws[w]; ws[w] = run; run += s; }
    }
    __syncthreads();
    x += ws[wid];              // inclusive over block
    int excl = x - v;
    if (base < NN) tmp[a * NN + base] = excl;
    if (base + 1 < NN) tmp[a * NN + base + 1] = excl + v0;
    if (t == 511) bsum[a * SB + b] = x;   // block total
}

__global__ __launch_bounds__(128) void scan_p2(int* __restrict__ bsum,
                                               int* __restrict__ out0,
                                               int* __restrict__ out1) {
    int t = threadIdx.x;
    int a = t >> 6, lane = t & 63;
    int v = (lane < SB) ? bsum[a * SB + lane] : 0;
    int x = v;
#pragma unroll
    for (int off = 1; off < 64; off <<= 1) {
        int u = __shfl_up(x, off);
        if (lane >= off) x += u;
    }
    if (lane < SB) bsum[a * SB + lane] = x - v;   // exclusive
    if (lane == SB - 1) {
        if (a == 0) out0[NN] = x; else out1[NN] = x;
    }
}

__global__ __launch_bounds__(512) void scan_p3(const int* __restrict__ tmp,
                                               const int* __restrict__ bsum,
                                               int* __restrict__ out0,
                                               int* __restrict__ out1) {
    int a = blockIdx.x / SB;
    int b = blockIdx.x % SB;
    int* out = a ? out1 : out0;
    int add = bsum[a * SB + b];
    int t = threadIdx.x;
    int base = b * 1024 + t * 2;
    if (base < NN) out[base] = tmp[a * NN + base] + add;
    if (base + 1 < NN) out[base + 1] = tmp[a * NN + base + 1] + add;
}

__global__ void init_node(const int* __restrict__ degin, const int* __restrict__ degout,
                          float* __restrict__ dis, float* __restrict__ cntf) {
    int i = blockIdx.x * blockDim.x + threadIdx.x;
    if (i < NN) {
        dis[i] = rsqrtf((float)(degin[i] + 1));   // +1 self loop; always >0
        int od = degout[i];
        cntf[i] = (float)(od > 0 ? od : 1);
    }
}

// Atomic-free, XCD-partitioned scatter: position = offset + precomputed rank.
// Partition p only writes CSR slices of its node range -> stores stay L2-local.
__global__ void fill_csr_part(const int* __restrict__ src, const int* __restrict__ dst,
                              const int* __restrict__ off_dst, const int* __restrict__ off_src,
                              const int* __restrict__ rank_in, const int* __restrict__ rank_out,
                              int* __restrict__ srcs_by_dst, int* __restrict__ dsts_by_src,
                              int nGroups) {
    int p = blockIdx.x & 7;
    int g = blockIdx.x >> 3;
    for (int e = g * 256 + threadIdx.x; e < NE; e += nGroups * 256) {
        int s = src[e], d = dst[e];
        if (d / PART_DIV == p) srcs_by_dst[off_dst[d] + rank_in[e]] = s;
        if (s / PART_DIV == p) dsts_by_src[off_src[s] + rank_out[e]] = d;
    }
}

// ---------------- GEMM: [n,K] @ [K,64], 64 rows per block (enc/dec) ----------------
template<int K, bool RELU, bool WSC>
__global__ __launch_bounds__(256) void gemm64b(const float* __restrict__ X,
                                               const float* __restrict__ W,
                                               const float* __restrict__ bias,
                                               const float* __restrict__ rowscale,
                                               float* __restrict__ out,
                                               unsigned short* __restrict__ xsc, int n) {
    __shared__ float Ws[64 * 64];
    __shared__ float Xs[64][68];
    int tid = threadIdx.x;
    int row0 = blockIdx.x * 64;
    int r16 = tid >> 4;
    int cg = tid & 15;
    float4 acc[4];
#pragma unroll
    for (int t = 0; t < 4; ++t) acc[t] = make_float4(0.f, 0.f, 0.f, 0.f);

    for (int kc = 0; kc < K; kc += 64) {
        const float4* W4 = (const float4*)(W + (size_t)kc * 64);
        float4* Ws4 = (float4*)Ws;
#pragma unroll
        for (int t = 0; t < 4; ++t) Ws4[tid + t * 256] = W4[tid + t * 256];
#pragma unroll
        for (int t = 0; t < 4; ++t) {
            int r = r16 + t * 16;
            int grow = row0 + r;
            float4 xv = make_float4(0.f, 0.f, 0.f, 0.f);
            if (grow < n) xv = *(const float4*)(X + (size_t)grow * K + kc + cg * 4);
            Xs[r][cg * 4 + 0] = xv.x; Xs[r][cg * 4 + 1] = xv.y;
            Xs[r][cg * 4 + 2] = xv.z; Xs[r][cg * 4 + 3] = xv.w;
        }
        __syncthreads();
#pragma unroll
        for (int k = 0; k < 64; ++k) {
            float4 w4 = ((const float4*)Ws)[k * 16 + cg];
#pragma unroll
            for (int t = 0; t < 4; ++t) {
                float xv = Xs[r16 + t * 16][k];
                acc[t].x += xv * w4.x; acc[t].y += xv * w4.y;
                acc[t].z += xv * w4.z; acc[t].w += xv * w4.w;
            }
        }
        __syncthreads();
    }

    float4 b4 = ((const float4*)bias)[cg];
#pragma unroll
    for (int t = 0; t < 4; ++t) {
        int row = row0 + r16 + t * 16;
        if (row < n) {
            float4 o;
            o.x = acc[t].x + b4.x; o.y = acc[t].y + b4.y;
            o.z = acc[t].z + b4.z; o.w = acc[t].w + b4.w;
            if (RELU) {
                o.x = fmaxf(o.x, 0.f); o.y = fmaxf(o.y, 0.f);
                o.z = fmaxf(o.z, 0.f); o.w = fmaxf(o.w, 0.f);
            }
            ((float4*)(out + (size_t)row * 64))[cg] = o;
            if (WSC) {
                float s = rowscale[row];
                float4 o2 = make_float4(o.x * s, o.y * s, o.z * s, o.w * s);
                ((ushort4*)(xsc + (size_t)row * 64))[cg] = f4_to_us4(o2);
            }
        }
    }
}

// ---------------- gemm64z: [n,64] @ [64,64] + relu, fp32 or bf16 out ----------------
template<bool OUTBF>
__global__ __launch_bounds__(256) void gemm64z(const float* __restrict__ Z,
                                               const float* __restrict__ W,
                                               const float* __restrict__ bias,
                                               float* __restrict__ outf,
                                               unsigned short* __restrict__ outb, int n) {
    __shared__ float Ws[64 * 64];
    __shared__ float Xs[64][68];
    int tid = threadIdx.x;
    int row0 = blockIdx.x * 64;
    int r16 = tid >> 4;
    int cg = tid & 15;
    float4 acc[4];
#pragma unroll
    for (int t = 0; t < 4; ++t) acc[t] = make_float4(0.f, 0.f, 0.f, 0.f);

    {
        const float4* W4 = (const float4*)W;
        float4* Ws4 = (float4*)Ws;
#pragma unroll
        for (int t = 0; t < 4; ++t) Ws4[tid + t * 256] = W4[tid + t * 256];
#pragma unroll
        for (int t = 0; t < 4; ++t) {
            int r = r16 + t * 16;
            int gr = row0 + r;
            float4 xv = make_float4(0.f, 0.f, 0.f, 0.f);
            if (gr < n) xv = *(const float4*)(Z + (size_t)gr * 64 + cg * 4);
            Xs[r][cg * 4 + 0] = xv.x; Xs[r][cg * 4 + 1] = xv.y;
            Xs[r][cg * 4 + 2] = xv.z; Xs[r][cg * 4 + 3] = xv.w;
        }
        __syncthreads();
#pragma unroll
        for (int k = 0; k < 64; ++k) {
            float4 w4 = ((const float4*)Ws)[k * 16 + cg];
#pragma unroll
            for (int t = 0; t < 4; ++t) {
                float xv = Xs[r16 + t * 16][k];
                acc[t].x += xv * w4.x; acc[t].y += xv * w4.y;
                acc[t].z += xv * w4.z; acc[t].w += xv * w4.w;
            }
        }
    }

    float4 b4 = ((const float4*)bias)[cg];
#pragma unroll
    for (int t = 0; t < 4; ++t) {
        int row = row0 + r16 + t * 16;
        if (row < n) {
            float4 o;
            o.x = fmaxf(acc[t].x + b4.x, 0.f); o.y = fmaxf(acc[t].y + b4.y, 0.f);
            o.z = fmaxf(acc[t].z + b4.z, 0.f); o.w = fmaxf(acc[t].w + b4.w, 0.f);
            if (OUTBF) {
                ((ushort4*)(outb + (size_t)row * 64))[cg] = f4_to_us4(o);
            } else {
                ((float4*)(outf + (size_t)row * 64))[cg] = o;
            }
        }
    }
}

// ---------------- zgather: node-per-octet, LDS-free, unroll 8 ----------------
__global__ __launch_bounds__(256) void zgather(
    const unsigned short* __restrict__ Xbf,
    const int* __restrict__ off, const int* __restrict__ nbr,
    const float* __restrict__ dis, float* __restrict__ Z)
{
    int t = blockIdx.x * 256 + threadIdx.x;
    int node = t >> 3, l8 = t & 7;
    if (node >= NN) return;
    const uint4* Xb = (const uint4*)Xbf;   // row = 8 uint4
    float a[8];
    unpack8(a, Xb[(size_t)node * 8 + l8]); // self (dis_i*X_i)
    int lo = off[node], hi = off[node + 1];
    int j = lo;
    for (; j + 7 < hi; j += 8) {
        int s0 = nbr[j],     s1 = nbr[j + 1], s2 = nbr[j + 2], s3 = nbr[j + 3];
        int s4 = nbr[j + 4], s5 = nbr[j + 5], s6 = nbr[j + 6], s7 = nbr[j + 7];
        uint4 r0 = Xb[(size_t)s0 * 8 + l8];
        uint4 r1 = Xb[(size_t)s1 * 8 + l8];
        uint4 r2 = Xb[(size_t)s2 * 8 + l8];
        uint4 r3 = Xb[(size_t)s3 * 8 + l8];
        uint4 r4 = Xb[(size_t)s4 * 8 + l8];
        uint4 r5 = Xb[(size_t)s5 * 8 + l8];
        uint4 r6 = Xb[(size_t)s6 * 8 + l8];
        uint4 r7 = Xb[(size_t)s7 * 8 + l8];
        acc8(a, r0); acc8(a, r1); acc8(a, r2); acc8(a, r3);
        acc8(a, r4); acc8(a, r5); acc8(a, r6); acc8(a, r7);
    }
    for (; j + 3 < hi; j += 4) {
        int s0 = nbr[j], s1 = nbr[j + 1], s2 = nbr[j + 2], s3 = nbr[j + 3];
        uint4 r0 = Xb[(size_t)s0 * 8 + l8];
        uint4 r1 = Xb[(size_t)s1 * 8 + l8];
        uint4 r2 = Xb[(size_t)s2 * 8 + l8];
        uint4 r3 = Xb[(size_t)s3 * 8 + l8];
        acc8(a, r0); acc8(a, r1); acc8(a, r2); acc8(a, r3);
    }
    for (; j < hi; ++j) {
        acc8(a, Xb[(size_t)nbr[j] * 8 + l8]);
    }
    float di = dis[node];
    float* zp = Z + (size_t)node * 64 + l8 * 8;
    *(float4*)(zp)     = make_float4(di * a[0], di * a[1], di * a[2], di * a[3]);
    *(float4*)(zp + 4) = make_float4(di * a[4], di * a[5], di * a[6], di * a[7]);
}

// ---------------- gate + convex update: node-per-octet, LDS-free, unroll 8 ----------------
__global__ __launch_bounds__(256) void gate_update8(
    const unsigned short* __restrict__ Cbf, const float* __restrict__ Xn,
    float* __restrict__ X, unsigned short* __restrict__ Xbf,
    const int* __restrict__ off, const int* __restrict__ nbr,
    const float* __restrict__ cntf, const float* __restrict__ dis)
{
    int t = blockIdx.x * 256 + threadIdx.x;
    int node = t >> 3, l8 = t & 7;
    if (node >= NN) return;
    const uint4* Cb = (const uint4*)Cbf;
    float xg[8];
    unpack8(xg, Cb[(size_t)node * 8 + l8]);
    float a[8] = {0.f, 0.f, 0.f, 0.f, 0.f, 0.f, 0.f, 0.f};
    int lo = off[node], hi = off[node + 1];
    int j = lo;
    for (; j + 7 < hi; j += 8) {
        int d0 = nbr[j],     d1 = nbr[j + 1], d2 = nbr[j + 2], d3 = nbr[j + 3];
        int d4 = nbr[j + 4], d5 = nbr[j + 5], d6 = nbr[j + 6], d7 = nbr[j + 7];
        uint4 r0 = Cb[(size_t)d0 * 8 + l8];
        uint4 r1 = Cb[(size_t)d1 * 8 + l8];
        uint4 r2 = Cb[(size_t)d2 * 8 + l8];
        uint4 r3 = Cb[(size_t)d3 * 8 + l8];
        uint4 r4 = Cb[(size_t)d4 * 8 + l8];
        uint4 r5 = Cb[(size_t)d5 * 8 + l8];
        uint4 r6 = Cb[(size_t)d6 * 8 + l8];
        uint4 r7 = Cb[(size_t)d7 * 8 + l8];
        accd8(a, xg, r0); accd8(a, xg, r1); accd8(a, xg, r2); accd8(a, xg, r3);
        accd8(a, xg, r4); accd8(a, xg, r5); accd8(a, xg, r6); accd8(a, xg, r7);
    }
    for (; j + 3 < hi; j += 4) {
        int d0 = nbr[j], d1 = nbr[j + 1], d2 = nbr[j + 2], d3 = nbr[j + 3];
        uint4 r0 = Cb[(size_t)d0 * 8 + l8];
        uint4 r1 = Cb[(size_t)d1 * 8 + l8];
        uint4 r2 = Cb[(size_t)d2 * 8 + l8];
        uint4 r3 = Cb[(size_t)d3 * 8 + l8];
        accd8(a, xg, r0); accd8(a, xg, r1); accd8(a, xg, r2); accd8(a, xg, r3);
    }
    for (; j < hi; ++j) {
        accd8(a, xg, Cb[(size_t)nbr[j] * 8 + l8]);
    }
    float inv = 1.f / cntf[node];
    float di = dis[node];
    const float* xop = X + (size_t)node * 64 + l8 * 8;
    const float* xnp = Xn + (size_t)node * 64 + l8 * 8;
    float o[8];
#pragma unroll
    for (int k = 0; k < 8; ++k) {
        float tau = tanh_pos(a[k] * inv);
        float xo = xop[k], xn = xnp[k];
        o[k] = xo + tau * (xn - xo);
    }
    float* xp = X + (size_t)node * 64 + l8 * 8;
    *(float4*)(xp)     = make_float4(o[0], o[1], o[2], o[3]);
    *(float4*)(xp + 4) = make_float4(o[4], o[5], o[6], o[7]);
    uint4 pk;
    pk.x = pack2bf(o[0] * di, o[1] * di);
    pk.y = pack2bf(o[2] * di, o[3] * di);
    pk.z = pack2bf(o[4] * di, o[5] * di);
    pk.w = pack2bf(o[6] * di, o[7] * di);
    ((uint4*)Xbf)[(size_t)node * 8 + l8] = pk;
}

// ---------------- launch ----------------

extern "C" void kernel_launch(void* const* d_in, const int* in_sizes, int n_in,
                              void* d_out, int out_size, void* d_ws, size_t ws_size,
                              hipStream_t stream) {
    const float* x      = (const float*)d_in[0];
    const int*   ei     = (const int*)d_in[1];
    const float* enc_w  = (const float*)d_in[2];
    const float* enc_b  = (const float*)d_in[3];
    const float* conv_w = (const float*)d_in[4];
    const float* conv_b = (const float*)d_in[5];
    const float* gg_w   = (const float*)d_in[6];
    const float* gg_b   = (const float*)d_in[7];
    const float* dec_w  = (const float*)d_in[8];
    const float* dec_b  = (const float*)d_in[9];
    float* out = (float*)d_out;

    const int* src = ei;
    const int* dst = ei + NE;

    char* p = (char*)d_ws;
    auto alloc = [&](size_t bytes) -> void* {
        void* r = (void*)p;
        p += (bytes + 255) & ~(size_t)255;
        return r;
    };
    float* X   = (float*)alloc((size_t)NN * 64 * 4);
    float* Zb  = (float*)alloc((size_t)NN * 64 * 4);           // Z (fp32)
    float* B   = (float*)alloc((size_t)NN * 64 * 4);           // X_ candidate (fp32)
    unsigned short* Xbf = (unsigned short*)alloc((size_t)NN * 64 * 2);  // dis*X, bf16
    unsigned short* Cbf = (unsigned short*)alloc((size_t)NN * 64 * 2);  // xg, bf16
    float* dis  = (float*)alloc((size_t)NN * 4);
    float* cntf = (float*)alloc((size_t)NN * 4);
    int* degin   = (int*)alloc((size_t)NN * 4);
    int* degout  = (int*)alloc((size_t)NN * 4);
    int* off_dst = (int*)alloc((size_t)(NN + 1) * 4);
    int* off_src = (int*)alloc((size_t)(NN + 1) * 4);
    int* rank_in  = (int*)alloc((size_t)NE * 4);
    int* rank_out = (int*)alloc((size_t)NE * 4);
    int* sbd     = (int*)alloc((size_t)NE * 4);   // srcs grouped by dst
    int* dbs     = (int*)alloc((size_t)NE * 4);   // dsts grouped by src
    int* stmp    = (int*)alloc((size_t)2 * NN * 4);  // scan temp
    int* bsum    = (int*)alloc((size_t)2 * SB * 4);  // scan block sums

    hipMemsetAsync(degin, 0, (size_t)NN * 4, stream);
    hipMemsetAsync(degout, 0, (size_t)NN * 4, stream);

    const int EB = (NE + 255) / 256;
    const int NB = (NN + 255) / 256;
    const int NGROUPS = 104;
    count_deg_rank<<<EB, 256, 0, stream>>>(src, dst, degin, degout, rank_in, rank_out);
    scan_p1<<<2 * SB, 512, 0, stream>>>(degin, degout, stmp, bsum);
    scan_p2<<<1, 128, 0, stream>>>(bsum, off_dst, off_src);
    scan_p3<<<2 * SB, 512, 0, stream>>>(stmp, bsum, off_dst, off_src);
    init_node<<<NB, 256, 0, stream>>>(degin, degout, dis, cntf);
    fill_csr_part<<<8 * NGROUPS, 256, 0, stream>>>(src, dst, off_dst, off_src,
                                                   rank_in, rank_out, sbd, dbs, NGROUPS);

    const int GB = (NN + 63) / 64;                 // 64-row gemm blocks
    const int OB = ((NN * 8) + 255) / 256;         // octet-kernel blocks (8 thr/node)

    // encoder: X = relu(x@enc_w+b); Xbf = bf16(dis*X)
    gemm64b<IND, true, true><<<GB, 256, 0, stream>>>(x, enc_w, enc_b, dis, X, Xbf, NN);

    for (int l = 0; l < DEPTH; ++l) {
        zgather<<<OB, 256, 0, stream>>>(Xbf, off_dst, sbd, dis, Zb);
        gemm64z<false><<<GB, 256, 0, stream>>>(Zb, conv_w, conv_b, B, nullptr, NN);
        gemm64z<true><<<GB, 256, 0, stream>>>(Zb, gg_w, gg_b, nullptr, Cbf, NN);
        gate_update8<<<OB, 256, 0, stream>>>(Cbf, B, X, Xbf, off_src, dbs, cntf, dis);
    }

    // decoder
    gemm64b<NH, true, false><<<GB, 256, 0, stream>>>(X, dec_w, dec_b, nullptr, out, nullptr, NN);
}